// Round 2
// baseline (4491.951 us; speedup 1.0000x reference)
//
#include <hip/hip_runtime.h>
#include <math.h>

// ViT Vector Quantizer: z [32,1024,32] f32, embedding [8192,32] f32.
// Outputs (concat, read as f32): z_q_out [N*D], loss [1], idx [N] (as floats).
//
// R8b: deferred-argmax MFMA pass + chunk rescore (resubmit of R8; prior round
// died to a container-acquisition failure, no kernel verdict).
//   K0 k_prep        : (unchanged) normalize codes/z, bf16 hi/lo swizzles.
//   K1 k_argmin_mfma : SWAPPED operands mfma(codes, z) so each lane's 4 scores
//                      share one z-row -> 2-op fmax tree replaces 20-op/tile
//                      argmax bookkeeping. 4 row-groups per wave -> each LDS
//                      code read feeds 12 MFMAs. Tracks only per-256-code-chunk
//                      max + (s1, best-chunk, other-chunk-2nd) per row-quarter.
//                      Grid 512 = 128 row-sets x 4 code-quarters, 2 blocks/CU.
//   K2 k_rescore     : merge 4 quarters/row, stage winning chunk (256 codes,
//                      fp32) in LDS, exact fp32 rescan (row-per-wave, 4 codes/
//                      lane) -> exact in-chunk argmax. Cross-chunk ambiguity
//                      (s2 > sC - MARGIN) -> sentinel + list for k_cleanup.
//   K3 k_cleanup     : (unchanged) full exact fp32 rescore for flagged rows.
//   K4 k_epi         : (unchanged) decode sentinel, gather, outputs.

#define D 32
#define KCODES 8192
#define MARGIN 2.5e-4f     // ~20x worst-case split-bf16 error bound
#define EPS 1e-12f

typedef short bf16x8 __attribute__((ext_vector_type(8)));
typedef unsigned short u16x8 __attribute__((ext_vector_type(8)));
typedef float f32x4 __attribute__((ext_vector_type(4)));

static __device__ __forceinline__ unsigned short f2bf(float x) {  // RNE bf16 bits
  unsigned u = __float_as_uint(x);
  return (unsigned short)((u + 0x7FFFu + ((u >> 16) & 1u)) >> 16);
}
static __device__ __forceinline__ float bf2f(unsigned short s) {
  return __uint_as_float(((unsigned)s) << 16);
}
static __device__ __forceinline__ void gload_lds16(const void* g, void* l) {
  __builtin_amdgcn_global_load_lds(
      (const __attribute__((address_space(1))) void*)g,
      (__attribute__((address_space(3))) void*)l, 16, 0, 0);
}

// MFMA fragment layouts (validated in prior rounds; A and B mappings are
// identical index formulas, so the same swizzled data serves either operand):
//   A[m][k]: m = lane&15, k = (lane>>4)*8 + j   (8 bf16/lane, contiguous 16B)
//   B[k][n]: n = lane&15, k = (lane>>4)*8 + j
//   C[m][n]: n = lane&15, m = (lane>>4)*4 + reg

__global__ __launch_bounds__(256) void k_prep(const float* __restrict__ z,
                                              const float* __restrict__ emb,
                                              float* __restrict__ en,
                                              float* __restrict__ en_h,
                                              unsigned short* __restrict__ eswz,
                                              unsigned short* __restrict__ zswz_hi,
                                              unsigned short* __restrict__ zswz_lo,
                                              int* __restrict__ cnt,
                                              float* __restrict__ loss,
                                              unsigned long long* __restrict__ mp2,
                                              int N) {
  int v = blockIdx.x * 256 + threadIdx.x;
  if (v == 0) { *cnt = 0; *loss = 0.f; }
  if (v >= KCODES + N) return;
  if (v >= KCODES) mp2[v - KCODES] = 0ull;   // atomicMax identity
  const float* src = (v < KCODES) ? (emb + (size_t)v * D) : (z + (size_t)(v - KCODES) * D);

  float x[D];
  const float4* p = reinterpret_cast<const float4*>(src);
#pragma unroll
  for (int j = 0; j < D / 4; ++j) {
    float4 q = p[j];
    x[4 * j + 0] = q.x; x[4 * j + 1] = q.y; x[4 * j + 2] = q.z; x[4 * j + 3] = q.w;
  }
  float ss = 0.f;
#pragma unroll
  for (int j = 0; j < D; ++j) ss = fmaf(x[j], x[j], ss);
  float n = fmaxf(sqrtf(ss), EPS);
#pragma unroll
  for (int j = 0; j < D; ++j) x[j] = x[j] / n;   // true division mirrors reference

  unsigned short hi[D], lo[D];
#pragma unroll
  for (int j = 0; j < D; ++j) {
    hi[j] = f2bf(x[j]);
    lo[j] = f2bf(x[j] - bf2f(hi[j]));   // x - bf16(x) exact in fp32
  }

  if (v < KCODES) {
    float4* o = reinterpret_cast<float4*>(en + (size_t)v * D);
    float s2 = 0.f;
#pragma unroll
    for (int j = 0; j < D / 4; ++j) {
      float4 q = {x[4 * j], x[4 * j + 1], x[4 * j + 2], x[4 * j + 3]};
      s2 = fmaf(q.x, q.x, fmaf(q.y, q.y, fmaf(q.z, q.z, fmaf(q.w, q.w, s2))));
      o[j] = q;
    }
    en_h[v] = 0.5f * s2;
    int tl = v >> 4, m = v & 15;    // fragment swizzle (tile-of-16 codes)
#pragma unroll
    for (int q = 0; q < 4; ++q) {
      u16x8 hv, lv;
#pragma unroll
      for (int j = 0; j < 8; ++j) { hv[j] = hi[8 * q + j]; lv[j] = lo[8 * q + j]; }
      *(u16x8*)(eswz + (size_t)tl * 1024 + (q * 16 + m) * 8) = hv;
      *(u16x8*)(eswz + (size_t)tl * 1024 + 512 + (q * 16 + m) * 8) = lv;
    }
  } else {
    int r = v - KCODES;
    int g = r >> 4, m = r & 15;     // fragment swizzle (group-of-16 rows)
#pragma unroll
    for (int q = 0; q < 4; ++q) {
      u16x8 hv, lv;
#pragma unroll
      for (int j = 0; j < 8; ++j) { hv[j] = hi[8 * q + j]; lv[j] = lo[8 * q + j]; }
      *(u16x8*)(zswz_hi + (size_t)g * 512 + (q * 16 + m) * 8) = hv;
      *(u16x8*)(zswz_lo + (size_t)g * 512 + (q * 16 + m) * 8) = lv;
    }
  }
}

// Deferred-argmax MFMA pass. Grid = (N/256) row-sets x 4 code-quarters.
// Block = 4 waves; each wave holds z-fragments for 4 row-groups (64 rows) so
// one A-fragment (codes) LDS read feeds 12 MFMAs. Per lane: 4 rows (one per
// row-group), 4 scores each per tile, reduced by a fmax tree into a per-chunk
// max. Only (s1, best chunk, other-chunk-2nd-best) survive per row-quarter.
__global__ __launch_bounds__(256, 2) void k_argmin_mfma(
    const unsigned short* __restrict__ zswz_hi,
    const unsigned short* __restrict__ zswz_lo,
    const unsigned short* __restrict__ eswz,
    float* __restrict__ res_s1, int* __restrict__ res_cb,
    float* __restrict__ res_s2) {
  __shared__ unsigned short lds_sh[2][16384];   // 2 x 32 KB double buffer

  const int tid = threadIdx.x;
  const int wid = tid >> 6, lane = tid & 63;
  const int lane15 = lane & 15, quad = lane >> 4;
  const int rs = blockIdx.x >> 2;               // row-set (256 rows)
  const int qt = blockIdx.x & 3;                // code quarter (8 chunks)

  bf16x8 zhi[4], zlo[4];
#pragma unroll
  for (int rg = 0; rg < 4; ++rg) {
    int g = rs * 16 + wid * 4 + rg;
    zhi[rg] = *(const bf16x8*)(zswz_hi + (size_t)g * 512 + lane * 8);
    zlo[rg] = *(const bf16x8*)(zswz_lo + (size_t)g * 512 + lane * 8);
  }

  float cm[4], s1g[4], s2c[4];
  int cb[4];
#pragma unroll
  for (int rg = 0; rg < 4; ++rg) {
    cm[rg] = -3.4e38f; s1g[rg] = -3.4e38f; s2c[rg] = -3.4e38f; cb[rg] = 0;
  }
  const f32x4 zero4 = {0.f, 0.f, 0.f, 0.f};

  const float4* gall = reinterpret_cast<const float4*>(eswz) + (size_t)qt * 8 * 2048;
#pragma unroll
  for (int i = 0; i < 8; ++i) {   // stage chunk 0 into buf 0
    int off = i * 256 + tid;      // wave-uniform base + lane-contiguous (m104)
    gload_lds16(gall + off, (char*)&lds_sh[0][0] + (size_t)off * 16);
  }

  for (int c = 0; c < 8; ++c) {
    __syncthreads();              // drains vmcnt -> buffer c&1 fully staged
    if (c + 1 < 8) {              // next DMA overlaps this chunk's compute
      const float4* gn = gall + (size_t)(c + 1) * 2048;
      char* dst = (char*)&lds_sh[(c + 1) & 1][0];
#pragma unroll
      for (int i = 0; i < 8; ++i) {
        int off = i * 256 + tid;
        gload_lds16(gn + off, dst + (size_t)off * 16);
      }
    }
    const unsigned short* buf = &lds_sh[c & 1][0];
#pragma unroll
    for (int t = 0; t < 16; ++t) {
      bf16x8 ahi = *(const bf16x8*)(buf + t * 1024 + lane * 8);
      bf16x8 alo = *(const bf16x8*)(buf + t * 1024 + 512 + lane * 8);
#pragma unroll
      for (int rg = 0; rg < 4; ++rg) {
        // A = codes, B = z: C[m][n] -> n=lane15 = row-in-group, m = code
        f32x4 acc = __builtin_amdgcn_mfma_f32_16x16x32_bf16(ahi, zhi[rg], zero4, 0, 0, 0);
        acc = __builtin_amdgcn_mfma_f32_16x16x32_bf16(ahi, zlo[rg], acc, 0, 0, 0);
        acc = __builtin_amdgcn_mfma_f32_16x16x32_bf16(alo, zhi[rg], acc, 0, 0, 0);
        cm[rg] = fmaxf(cm[rg],
                       fmaxf(fmaxf(acc[0], acc[1]), fmaxf(acc[2], acc[3])));
      }
    }
    // chunk end: fold chunk max into (s1, best chunk, 2nd-best-chunk-max)
#pragma unroll
    for (int rg = 0; rg < 4; ++rg) {
      float old1 = s1g[rg];
      s2c[rg] = fmaxf(s2c[rg], fminf(cm[rg], old1));
      bool better = cm[rg] > old1;                // strict: earlier chunk on tie
      cb[rg] = better ? (qt * 8 + c) : cb[rg];
      s1g[rg] = better ? cm[rg] : old1;
      cm[rg] = -3.4e38f;
    }
  }

  // merge the 4 quads (disjoint code subsets of same rows): xor 16 then 32
#pragma unroll
  for (int m = 16; m <= 32; m <<= 1) {
#pragma unroll
    for (int rg = 0; rg < 4; ++rg) {
      float o1 = __shfl_xor(s1g[rg], m, 64);
      float o2 = __shfl_xor(s2c[rg], m, 64);
      int ob = __shfl_xor(cb[rg], m, 64);
      s2c[rg] = fmaxf(fmaxf(s2c[rg], o2), fminf(s1g[rg], o1));
      bool better = o1 > s1g[rg];
      s1g[rg] = better ? o1 : s1g[rg];
      cb[rg] = better ? ob : cb[rg];
    }
  }
  if (quad == 0) {
#pragma unroll
    for (int rg = 0; rg < 4; ++rg) {
      int row = rs * 256 + wid * 64 + rg * 16 + lane15;
      res_s1[(size_t)row * 4 + qt] = s1g[rg];
      res_cb[(size_t)row * 4 + qt] = cb[rg];
      res_s2[(size_t)row * 4 + qt] = s2c[rg];
    }
  }
}

// Exact fp32 rescore of each row's winning 256-code chunk.
// Grid = 32 chunks x 16 row-ranges. Block stages its chunk (fp32, padded
// stride 36 for conflict-free b128 LDS reads), scans its 2048-row range
// merging the 4 quarter-results, collects matching rows, then row-per-wave:
// 4 codes/lane, packed u64 wave argmax (max s, tie -> min k).
// Cross-chunk ambiguity (s2 > sC - MARGIN) -> sentinel + list for k_cleanup.
__global__ __launch_bounds__(256) void k_rescore(
    const float* __restrict__ z, const float* __restrict__ en,
    const float* __restrict__ en_h,
    const float* __restrict__ res_s1, const int* __restrict__ res_cb,
    const float* __restrict__ res_s2,
    int* __restrict__ idx_ws, int* __restrict__ list, int* __restrict__ cnt,
    int N) {
  __shared__ float en_s[256 * 36];     // [code][36] padded, 16B-aligned rows
  __shared__ float enh_s[256];
  __shared__ int rows_s[2048];
  __shared__ float s2_s[2048];
  __shared__ int nmatch;

  const int tid = threadIdx.x;
  const int c = blockIdx.x >> 4;       // chunk 0..31
  const int sb = blockIdx.x & 15;      // row sub-range
  const int rows_per = N >> 4;         // 2048
  const int r0 = sb * rows_per;

  if (tid == 0) nmatch = 0;
  // stage chunk: 2048 float4 of en -> padded LDS
  const float4* e4 = reinterpret_cast<const float4*>(en) + (size_t)c * 2048;
#pragma unroll
  for (int i = 0; i < 8; ++i) {
    int idx = i * 256 + tid;
    float4 v4 = e4[idx];
    int code = idx >> 3, j = idx & 7;
    *reinterpret_cast<float4*>(&en_s[code * 36 + j * 4]) = v4;
  }
  enh_s[tid] = en_h[c * 256 + tid];
  __syncthreads();

  // scan rows: merge 4 quarter-results, collect rows whose best chunk == c
  for (int i = 0; i < rows_per / 256; ++i) {
    int row = r0 + i * 256 + tid;
    float s1b = res_s1[(size_t)row * 4 + 0];
    int cbb = res_cb[(size_t)row * 4 + 0];
    float s2b = res_s2[(size_t)row * 4 + 0];
#pragma unroll
    for (int p = 1; p < 4; ++p) {
      float s1p = res_s1[(size_t)row * 4 + p];
      float s2p = res_s2[(size_t)row * 4 + p];
      int cbp = res_cb[(size_t)row * 4 + p];
      s2b = fmaxf(fmaxf(s2b, s2p), fminf(s1b, s1p));
      bool better = s1p > s1b;
      s1b = better ? s1p : s1b;
      cbb = better ? cbp : cbb;
    }
    if (cbb == c) {
      int pos = atomicAdd(&nmatch, 1);
      rows_s[pos] = row;
      s2_s[pos] = s2b;
    }
  }
  __syncthreads();
  const int nm = nmatch;
  const int lane = tid & 63, wid = tid >> 6;

  for (int ri = wid; ri < nm; ri += 4) {
    int row = __builtin_amdgcn_readfirstlane(rows_s[ri]);  // wave-uniform -> scalar loads
    const float* zr = z + (size_t)row * D;
    float v[D];
    float ss = 0.f;
#pragma unroll
    for (int d = 0; d < D; ++d) v[d] = zr[d];
#pragma unroll
    for (int d = 0; d < D; ++d) ss = fmaf(v[d], v[d], ss);
    float n = fmaxf(sqrtf(ss), EPS);
#pragma unroll
    for (int d = 0; d < D; ++d) v[d] = v[d] / n;   // matches k_cleanup/reference

    unsigned long long best = 0ull;
#pragma unroll
    for (int cc = 0; cc < 4; ++cc) {
      int kl = lane + cc * 64;
      float a = -enh_s[kl];
      const float* ep = &en_s[kl * 36];
#pragma unroll
      for (int jj = 0; jj < 8; ++jj) {             // exact k_cleanup fma order
        float4 e = *reinterpret_cast<const float4*>(&ep[jj * 4]);
        a = fmaf(v[4 * jj + 0], e.x, a);
        a = fmaf(v[4 * jj + 1], e.y, a);
        a = fmaf(v[4 * jj + 2], e.z, a);
        a = fmaf(v[4 * jj + 3], e.w, a);
      }
      int k = c * 256 + kl;
      unsigned o = __float_as_uint(a);
      o = (o & 0x80000000u) ? ~o : (o | 0x80000000u);
      unsigned long long pk = ((unsigned long long)o << 32) | (unsigned)(8191 - k);
      best = (pk > best) ? pk : best;
    }
#pragma unroll
    for (int m = 32; m >= 1; m >>= 1) {
      unsigned long long op = __shfl_xor(best, m, 64);
      best = (op > best) ? op : best;              // max s, tie -> min k
    }
    if (lane == 0) {
      unsigned uo = (unsigned)(best >> 32);
      unsigned uu = (uo & 0x80000000u) ? (uo & 0x7FFFFFFFu) : ~uo;
      float sC = __uint_as_float(uu);
      int kC = 8191 - (int)(unsigned)(best & 0xFFFFFFFFull);
      if (s2_s[ri] > sC - MARGIN) {                // another chunk may win
        int pos = atomicAdd(cnt, 1);
        list[pos] = row;
        idx_ws[row] = -(pos + 1);                  // sentinel: resolved via mp2
      } else {
        idx_ws[row] = kC;
      }
    }
  }
}

// Exact fp32 rescore, THREAD-PER-CODE: task j = (flag i, k-chunk kc); each of the
// 256 threads scores one code; block-reduce; one atomicMax(mp2[i]) per block.
__global__ __launch_bounds__(256) void k_cleanup(const float* __restrict__ z,
                                                 const float* __restrict__ en,
                                                 const float* __restrict__ en_h,
                                                 const int* __restrict__ list,
                                                 const int* __restrict__ cnt,
                                                 unsigned long long* __restrict__ mp2) {
  __shared__ unsigned long long wred[4];
  const int tid = threadIdx.x;
  const int lane = tid & 63, wid = tid >> 6;
  const int ntask = (*cnt) * 32;               // 32 chunks of 256 codes per row

  for (int j = blockIdx.x; j < ntask; j += gridDim.x) {
    int i = j >> 5, kc = j & 31;
    int row = list[i];
    const float* zr = z + (size_t)row * D;     // wave-uniform -> scalar loads
    float v[D];
    float ss = 0.f;
#pragma unroll
    for (int d = 0; d < D; ++d) v[d] = zr[d];
#pragma unroll
    for (int d = 0; d < D; ++d) ss = fmaf(v[d], v[d], ss);
    float n = fmaxf(sqrtf(ss), EPS);
#pragma unroll
    for (int d = 0; d < D; ++d) v[d] = v[d] / n;

    int k = kc * 256 + tid;                    // contiguous rows -> coalesced
    const float4* er = reinterpret_cast<const float4*>(en + (size_t)k * D);
    float a = -en_h[k];
#pragma unroll
    for (int jj = 0; jj < 8; ++jj) {           // exact R4 fma order
      float4 e = er[jj];
      a = fmaf(v[4 * jj + 0], e.x, a);
      a = fmaf(v[4 * jj + 1], e.y, a);
      a = fmaf(v[4 * jj + 2], e.z, a);
      a = fmaf(v[4 * jj + 3], e.w, a);
    }
    unsigned o = __float_as_uint(a);
    o = (o & 0x80000000u) ? ~o : (o | 0x80000000u);
    unsigned long long pk = ((unsigned long long)o << 32) | (unsigned)(8191 - k);
#pragma unroll
    for (int m = 32; m >= 1; m >>= 1) {
      unsigned long long op = __shfl_xor(pk, m, 64);
      pk = (op > pk) ? op : pk;                // max s, tie -> min k
    }
    if (lane == 0) wred[wid] = pk;
    __syncthreads();
    if (tid == 0) {
      unsigned long long m01 = (wred[0] > wred[1]) ? wred[0] : wred[1];
      unsigned long long m23 = (wred[2] > wred[3]) ? wred[2] : wred[3];
      atomicMax(&mp2[i], (m01 > m23) ? m01 : m23);
    }
    __syncthreads();                           // protect wred for next task
  }
}

__global__ __launch_bounds__(256) void k_epi(const float* __restrict__ z,
                                             const float* __restrict__ en,
                                             const int* __restrict__ idx_ws,
                                             const unsigned long long* __restrict__ mp2,
                                             float* __restrict__ out_z,
                                             float* __restrict__ loss,
                                             float* __restrict__ out_idx,
                                             float scale) {
  int row = blockIdx.x * 256 + threadIdx.x;
  int kb = idx_ws[row];
  if (kb < 0) {                                // flagged: exact result in mp2
    unsigned long long m = mp2[-kb - 1];
    kb = 8191 - (int)(unsigned)(m & 0xFFFFFFFFull);
  }
  out_idx[row] = (float)kb;  // whole out buffer read back as f32

  const float4* p = reinterpret_cast<const float4*>(z + (size_t)row * D);
  float4 q[D / 4];
#pragma unroll
  for (int j = 0; j < D / 4; ++j) q[j] = p[j];
  float ss = 0.f;
#pragma unroll
  for (int j = 0; j < D / 4; ++j)
    ss = fmaf(q[j].x, q[j].x, fmaf(q[j].y, q[j].y, fmaf(q[j].z, q[j].z, fmaf(q[j].w, q[j].w, ss))));
  float n = fmaxf(sqrtf(ss), EPS);

  const float4* ep = reinterpret_cast<const float4*>(en + (size_t)kb * D);
  float4* op = reinterpret_cast<float4*>(out_z + (size_t)row * D);
  float s = 0.f;
#pragma unroll
  for (int j = 0; j < D / 4; ++j) {
    float4 e = ep[j];
    float4 o;
    o.x = q[j].x + (e.x - q[j].x);  // STE forward value, reference op order
    o.y = q[j].y + (e.y - q[j].y);
    o.z = q[j].z + (e.z - q[j].z);
    o.w = q[j].w + (e.w - q[j].w);
    op[j] = o;
    float dx = e.x - q[j].x / n;  float dy = e.y - q[j].y / n;
    float dz = e.z - q[j].z / n;  float dw = e.w - q[j].w / n;
    s = fmaf(dx, dx, fmaf(dy, dy, fmaf(dz, dz, fmaf(dw, dw, s))));
  }

#pragma unroll
  for (int off = 32; off > 0; off >>= 1) s += __shfl_down(s, off, 64);
  __shared__ float wsum[4];
  int lane = threadIdx.x & 63, wid = threadIdx.x >> 6;
  if (lane == 0) wsum[wid] = s;
  __syncthreads();
  if (threadIdx.x == 0) {
    float tt = (wsum[0] + wsum[1]) + (wsum[2] + wsum[3]);
    atomicAdd(loss, tt * scale);
  }
}

extern "C" void kernel_launch(void* const* d_in, const int* in_sizes, int n_in,
                              void* d_out, int out_size, void* d_ws, size_t ws_size,
                              hipStream_t stream) {
  const float* z = (const float*)d_in[0];
  const float* emb = (const float*)d_in[1];
  const int N = in_sizes[0] / D;  // 32768
  const int K = in_sizes[1] / D;  // 8192

  float* out = (float*)d_out;
  float* out_z = out;                        // N*D
  float* loss = out + (size_t)N * D;         // 1
  float* out_idx = out + (size_t)N * D + 1;  // N

  // ws layout (~8.2 MB; R3/R4 WRITE_SIZE proves ws >= 9.4 MB)
  char* w = (char*)d_ws;
  float* en = (float*)w;                         w += (size_t)K * D * 4;     // 1 MB
  float* en_h = (float*)w;                       w += (size_t)K * 4;         // 32 KB
  unsigned short* eswz = (unsigned short*)w;     w += (size_t)K * D * 2 * 2; // 1 MB
  unsigned short* zswz_hi = (unsigned short*)w;  w += (size_t)N * D * 2;     // 2 MB
  unsigned short* zswz_lo = (unsigned short*)w;  w += (size_t)N * D * 2;     // 2 MB
  int* idx_ws = (int*)w;                         w += (size_t)N * 4;         // 128 KB
  int* list = (int*)w;                           w += (size_t)N * 4;         // 128 KB
  unsigned long long* mp2 = (unsigned long long*)w; w += (size_t)N * 8;      // 256 KB
  float* res_s1 = (float*)w;                     w += (size_t)N * 4 * 4;     // 512 KB
  int* res_cb = (int*)w;                         w += (size_t)N * 4 * 4;     // 512 KB
  float* res_s2 = (float*)w;                     w += (size_t)N * 4 * 4;     // 512 KB
  int* cnt = (int*)w;

  k_prep<<<dim3((K + N) / 256), 256, 0, stream>>>(
      z, emb, en, en_h, eswz, zswz_hi, zswz_lo, cnt, loss, mp2, N);

  k_argmin_mfma<<<dim3((N / 256) * 4), 256, 0, stream>>>(
      zswz_hi, zswz_lo, eswz, res_s1, res_cb, res_s2);

  k_rescore<<<dim3(32 * 16), 256, 0, stream>>>(
      z, en, en_h, res_s1, res_cb, res_s2, idx_ws, list, cnt, N);

  k_cleanup<<<dim3(4096), 256, 0, stream>>>(z, en, en_h, list, cnt, mp2);

  k_epi<<<dim3(N / 256), 256, 0, stream>>>(
      z, en, idx_ws, mp2, out_z, loss, out_idx, 1.25f / (float)((size_t)N * D));
}

// Round 3
// 199.629 us; speedup vs baseline: 22.5015x; 22.5015x over previous
//
#include <hip/hip_runtime.h>
#include <math.h>

// ViT Vector Quantizer: z [32,1024,32] f32, embedding [8192,32] f32.
// Outputs (concat, read as f32): z_q_out [N*D], loss [1], idx [N] (as floats).
//
// R9: fix R8's flag-test scale mismatch. The MFMA pass tracks raw dot products
// (codes are L2-normalized, so argmax dot == argmin dist), but k_rescore's
// exact score is dot - 0.5||e||^2 (the k_cleanup convention). R8 compared
// s2 (a dot, ~cos) against sC (~cos - 0.5): always true -> every row flagged
// -> 4.5 ms k_cleanup. Fix: add the winner's en_h back (dotw = sC + en_h[kC])
// and compare s2 > dotw - MARGIN. Everything else unchanged from R8b.
//   K0 k_prep        : normalize codes/z, bf16 hi/lo swizzles.
//   K1 k_argmin_mfma : swapped-operand mfma(codes, z), fmax-tree, per-chunk
//                      deferred argmax; grid 512 = 128 row-sets x 4 quarters.
//   K2 k_rescore     : merge quarters, stage winning chunk fp32 in LDS, exact
//                      in-chunk argmax; cross-chunk ambiguity -> k_cleanup.
//   K3 k_cleanup     : full exact fp32 rescore for flagged rows.
//   K4 k_epi         : decode sentinel, gather, outputs.

#define D 32
#define KCODES 8192
#define MARGIN 2.5e-4f     // ~20x worst-case split-bf16 error bound
#define EPS 1e-12f

typedef short bf16x8 __attribute__((ext_vector_type(8)));
typedef unsigned short u16x8 __attribute__((ext_vector_type(8)));
typedef float f32x4 __attribute__((ext_vector_type(4)));

static __device__ __forceinline__ unsigned short f2bf(float x) {  // RNE bf16 bits
  unsigned u = __float_as_uint(x);
  return (unsigned short)((u + 0x7FFFu + ((u >> 16) & 1u)) >> 16);
}
static __device__ __forceinline__ float bf2f(unsigned short s) {
  return __uint_as_float(((unsigned)s) << 16);
}
static __device__ __forceinline__ void gload_lds16(const void* g, void* l) {
  __builtin_amdgcn_global_load_lds(
      (const __attribute__((address_space(1))) void*)g,
      (__attribute__((address_space(3))) void*)l, 16, 0, 0);
}

// MFMA fragment layouts (validated in prior rounds; A and B mappings are
// identical index formulas, so the same swizzled data serves either operand):
//   A[m][k]: m = lane&15, k = (lane>>4)*8 + j   (8 bf16/lane, contiguous 16B)
//   B[k][n]: n = lane&15, k = (lane>>4)*8 + j
//   C[m][n]: n = lane&15, m = (lane>>4)*4 + reg

__global__ __launch_bounds__(256) void k_prep(const float* __restrict__ z,
                                              const float* __restrict__ emb,
                                              float* __restrict__ en,
                                              float* __restrict__ en_h,
                                              unsigned short* __restrict__ eswz,
                                              unsigned short* __restrict__ zswz_hi,
                                              unsigned short* __restrict__ zswz_lo,
                                              int* __restrict__ cnt,
                                              float* __restrict__ loss,
                                              unsigned long long* __restrict__ mp2,
                                              int N) {
  int v = blockIdx.x * 256 + threadIdx.x;
  if (v == 0) { *cnt = 0; *loss = 0.f; }
  if (v >= KCODES + N) return;
  if (v >= KCODES) mp2[v - KCODES] = 0ull;   // atomicMax identity
  const float* src = (v < KCODES) ? (emb + (size_t)v * D) : (z + (size_t)(v - KCODES) * D);

  float x[D];
  const float4* p = reinterpret_cast<const float4*>(src);
#pragma unroll
  for (int j = 0; j < D / 4; ++j) {
    float4 q = p[j];
    x[4 * j + 0] = q.x; x[4 * j + 1] = q.y; x[4 * j + 2] = q.z; x[4 * j + 3] = q.w;
  }
  float ss = 0.f;
#pragma unroll
  for (int j = 0; j < D; ++j) ss = fmaf(x[j], x[j], ss);
  float n = fmaxf(sqrtf(ss), EPS);
#pragma unroll
  for (int j = 0; j < D; ++j) x[j] = x[j] / n;   // true division mirrors reference

  unsigned short hi[D], lo[D];
#pragma unroll
  for (int j = 0; j < D; ++j) {
    hi[j] = f2bf(x[j]);
    lo[j] = f2bf(x[j] - bf2f(hi[j]));   // x - bf16(x) exact in fp32
  }

  if (v < KCODES) {
    float4* o = reinterpret_cast<float4*>(en + (size_t)v * D);
    float s2 = 0.f;
#pragma unroll
    for (int j = 0; j < D / 4; ++j) {
      float4 q = {x[4 * j], x[4 * j + 1], x[4 * j + 2], x[4 * j + 3]};
      s2 = fmaf(q.x, q.x, fmaf(q.y, q.y, fmaf(q.z, q.z, fmaf(q.w, q.w, s2))));
      o[j] = q;
    }
    en_h[v] = 0.5f * s2;
    int tl = v >> 4, m = v & 15;    // fragment swizzle (tile-of-16 codes)
#pragma unroll
    for (int q = 0; q < 4; ++q) {
      u16x8 hv, lv;
#pragma unroll
      for (int j = 0; j < 8; ++j) { hv[j] = hi[8 * q + j]; lv[j] = lo[8 * q + j]; }
      *(u16x8*)(eswz + (size_t)tl * 1024 + (q * 16 + m) * 8) = hv;
      *(u16x8*)(eswz + (size_t)tl * 1024 + 512 + (q * 16 + m) * 8) = lv;
    }
  } else {
    int r = v - KCODES;
    int g = r >> 4, m = r & 15;     // fragment swizzle (group-of-16 rows)
#pragma unroll
    for (int q = 0; q < 4; ++q) {
      u16x8 hv, lv;
#pragma unroll
      for (int j = 0; j < 8; ++j) { hv[j] = hi[8 * q + j]; lv[j] = lo[8 * q + j]; }
      *(u16x8*)(zswz_hi + (size_t)g * 512 + (q * 16 + m) * 8) = hv;
      *(u16x8*)(zswz_lo + (size_t)g * 512 + (q * 16 + m) * 8) = lv;
    }
  }
}

// Deferred-argmax MFMA pass. Grid = (N/256) row-sets x 4 code-quarters.
// Block = 4 waves; each wave holds z-fragments for 4 row-groups (64 rows) so
// one A-fragment (codes) LDS read feeds 12 MFMAs. Per lane: 4 rows (one per
// row-group), 4 scores each per tile, reduced by a fmax tree into a per-chunk
// max. Only (s1, best chunk, other-partial-2nd-best) survive per row-quarter.
__global__ __launch_bounds__(256, 2) void k_argmin_mfma(
    const unsigned short* __restrict__ zswz_hi,
    const unsigned short* __restrict__ zswz_lo,
    const unsigned short* __restrict__ eswz,
    float* __restrict__ res_s1, int* __restrict__ res_cb,
    float* __restrict__ res_s2) {
  __shared__ unsigned short lds_sh[2][16384];   // 2 x 32 KB double buffer

  const int tid = threadIdx.x;
  const int wid = tid >> 6, lane = tid & 63;
  const int lane15 = lane & 15, quad = lane >> 4;
  const int rs = blockIdx.x >> 2;               // row-set (256 rows)
  const int qt = blockIdx.x & 3;                // code quarter (8 chunks)

  bf16x8 zhi[4], zlo[4];
#pragma unroll
  for (int rg = 0; rg < 4; ++rg) {
    int g = rs * 16 + wid * 4 + rg;
    zhi[rg] = *(const bf16x8*)(zswz_hi + (size_t)g * 512 + lane * 8);
    zlo[rg] = *(const bf16x8*)(zswz_lo + (size_t)g * 512 + lane * 8);
  }

  float cm[4], s1g[4], s2c[4];
  int cb[4];
#pragma unroll
  for (int rg = 0; rg < 4; ++rg) {
    cm[rg] = -3.4e38f; s1g[rg] = -3.4e38f; s2c[rg] = -3.4e38f; cb[rg] = 0;
  }
  const f32x4 zero4 = {0.f, 0.f, 0.f, 0.f};

  const float4* gall = reinterpret_cast<const float4*>(eswz) + (size_t)qt * 8 * 2048;
#pragma unroll
  for (int i = 0; i < 8; ++i) {   // stage chunk 0 into buf 0
    int off = i * 256 + tid;      // wave-uniform base + lane-contiguous (m104)
    gload_lds16(gall + off, (char*)&lds_sh[0][0] + (size_t)off * 16);
  }

  for (int c = 0; c < 8; ++c) {
    __syncthreads();              // drains vmcnt -> buffer c&1 fully staged
    if (c + 1 < 8) {              // next DMA overlaps this chunk's compute
      const float4* gn = gall + (size_t)(c + 1) * 2048;
      char* dst = (char*)&lds_sh[(c + 1) & 1][0];
#pragma unroll
      for (int i = 0; i < 8; ++i) {
        int off = i * 256 + tid;
        gload_lds16(gn + off, dst + (size_t)off * 16);
      }
    }
    const unsigned short* buf = &lds_sh[c & 1][0];
#pragma unroll
    for (int t = 0; t < 16; ++t) {
      bf16x8 ahi = *(const bf16x8*)(buf + t * 1024 + lane * 8);
      bf16x8 alo = *(const bf16x8*)(buf + t * 1024 + 512 + lane * 8);
#pragma unroll
      for (int rg = 0; rg < 4; ++rg) {
        // A = codes, B = z: C[m][n] -> n=lane15 = row-in-group, m = code
        f32x4 acc = __builtin_amdgcn_mfma_f32_16x16x32_bf16(ahi, zhi[rg], zero4, 0, 0, 0);
        acc = __builtin_amdgcn_mfma_f32_16x16x32_bf16(ahi, zlo[rg], acc, 0, 0, 0);
        acc = __builtin_amdgcn_mfma_f32_16x16x32_bf16(alo, zhi[rg], acc, 0, 0, 0);
        cm[rg] = fmaxf(cm[rg],
                       fmaxf(fmaxf(acc[0], acc[1]), fmaxf(acc[2], acc[3])));
      }
    }
    // chunk end: fold chunk max into (s1, best chunk, 2nd-best-partial-max)
#pragma unroll
    for (int rg = 0; rg < 4; ++rg) {
      float old1 = s1g[rg];
      s2c[rg] = fmaxf(s2c[rg], fminf(cm[rg], old1));
      bool better = cm[rg] > old1;                // strict: earlier chunk on tie
      cb[rg] = better ? (qt * 8 + c) : cb[rg];
      s1g[rg] = better ? cm[rg] : old1;
      cm[rg] = -3.4e38f;
    }
  }

  // merge the 4 quads (disjoint code subsets of same rows): xor 16 then 32
#pragma unroll
  for (int m = 16; m <= 32; m <<= 1) {
#pragma unroll
    for (int rg = 0; rg < 4; ++rg) {
      float o1 = __shfl_xor(s1g[rg], m, 64);
      float o2 = __shfl_xor(s2c[rg], m, 64);
      int ob = __shfl_xor(cb[rg], m, 64);
      s2c[rg] = fmaxf(fmaxf(s2c[rg], o2), fminf(s1g[rg], o1));
      bool better = o1 > s1g[rg];
      s1g[rg] = better ? o1 : s1g[rg];
      cb[rg] = better ? ob : cb[rg];
    }
  }
  if (quad == 0) {
#pragma unroll
    for (int rg = 0; rg < 4; ++rg) {
      int row = rs * 256 + wid * 64 + rg * 16 + lane15;
      res_s1[(size_t)row * 4 + qt] = s1g[rg];
      res_cb[(size_t)row * 4 + qt] = cb[rg];
      res_s2[(size_t)row * 4 + qt] = s2c[rg];
    }
  }
}

// Exact fp32 rescore of each row's winning 256-code chunk.
// Grid = 32 chunks x 16 row-ranges. Block stages its chunk (fp32, padded
// stride 36), scans its 2048-row range merging the 4 quarter-results,
// collects matching rows, then row-per-wave: 4 codes/lane, packed u64 wave
// argmax (max s, tie -> min k). Flag test compares LIKE WITH LIKE: s2 (raw
// approx dot) vs dotw = sC + en_h[kC] (winner's raw exact dot).
__global__ __launch_bounds__(256) void k_rescore(
    const float* __restrict__ z, const float* __restrict__ en,
    const float* __restrict__ en_h,
    const float* __restrict__ res_s1, const int* __restrict__ res_cb,
    const float* __restrict__ res_s2,
    int* __restrict__ idx_ws, int* __restrict__ list, int* __restrict__ cnt,
    int N) {
  __shared__ float en_s[256 * 36];     // [code][36] padded, 16B-aligned rows
  __shared__ float enh_s[256];
  __shared__ int rows_s[2048];
  __shared__ float s2_s[2048];
  __shared__ int nmatch;

  const int tid = threadIdx.x;
  const int c = blockIdx.x >> 4;       // chunk 0..31
  const int sb = blockIdx.x & 15;      // row sub-range
  const int rows_per = N >> 4;         // 2048
  const int r0 = sb * rows_per;

  if (tid == 0) nmatch = 0;
  // stage chunk: 2048 float4 of en -> padded LDS
  const float4* e4 = reinterpret_cast<const float4*>(en) + (size_t)c * 2048;
#pragma unroll
  for (int i = 0; i < 8; ++i) {
    int idx = i * 256 + tid;
    float4 v4 = e4[idx];
    int code = idx >> 3, j = idx & 7;
    *reinterpret_cast<float4*>(&en_s[code * 36 + j * 4]) = v4;
  }
  enh_s[tid] = en_h[c * 256 + tid];
  __syncthreads();

  // scan rows: merge 4 quarter-results, collect rows whose best chunk == c
  for (int i = 0; i < rows_per / 256; ++i) {
    int row = r0 + i * 256 + tid;
    float s1b = res_s1[(size_t)row * 4 + 0];
    int cbb = res_cb[(size_t)row * 4 + 0];
    float s2b = res_s2[(size_t)row * 4 + 0];
#pragma unroll
    for (int p = 1; p < 4; ++p) {
      float s1p = res_s1[(size_t)row * 4 + p];
      float s2p = res_s2[(size_t)row * 4 + p];
      int cbp = res_cb[(size_t)row * 4 + p];
      s2b = fmaxf(fmaxf(s2b, s2p), fminf(s1b, s1p));
      bool better = s1p > s1b;
      s1b = better ? s1p : s1b;
      cbb = better ? cbp : cbb;
    }
    if (cbb == c) {
      int pos = atomicAdd(&nmatch, 1);
      rows_s[pos] = row;
      s2_s[pos] = s2b;
    }
  }
  __syncthreads();
  const int nm = nmatch;
  const int lane = tid & 63, wid = tid >> 6;

  for (int ri = wid; ri < nm; ri += 4) {
    int row = __builtin_amdgcn_readfirstlane(rows_s[ri]);  // wave-uniform -> scalar loads
    const float* zr = z + (size_t)row * D;
    float v[D];
    float ss = 0.f;
#pragma unroll
    for (int d = 0; d < D; ++d) v[d] = zr[d];
#pragma unroll
    for (int d = 0; d < D; ++d) ss = fmaf(v[d], v[d], ss);
    float n = fmaxf(sqrtf(ss), EPS);
#pragma unroll
    for (int d = 0; d < D; ++d) v[d] = v[d] / n;   // matches k_cleanup/reference

    unsigned long long best = 0ull;
#pragma unroll
    for (int cc = 0; cc < 4; ++cc) {
      int kl = lane + cc * 64;
      float a = -enh_s[kl];
      const float* ep = &en_s[kl * 36];
#pragma unroll
      for (int jj = 0; jj < 8; ++jj) {             // exact k_cleanup fma order
        float4 e = *reinterpret_cast<const float4*>(&ep[jj * 4]);
        a = fmaf(v[4 * jj + 0], e.x, a);
        a = fmaf(v[4 * jj + 1], e.y, a);
        a = fmaf(v[4 * jj + 2], e.z, a);
        a = fmaf(v[4 * jj + 3], e.w, a);
      }
      int k = c * 256 + kl;
      unsigned o = __float_as_uint(a);
      o = (o & 0x80000000u) ? ~o : (o | 0x80000000u);
      unsigned long long pk = ((unsigned long long)o << 32) | (unsigned)(8191 - k);
      best = (pk > best) ? pk : best;
    }
#pragma unroll
    for (int m = 32; m >= 1; m >>= 1) {
      unsigned long long op = __shfl_xor(best, m, 64);
      best = (op > best) ? op : best;              // max s, tie -> min k
    }
    if (lane == 0) {
      unsigned uo = (unsigned)(best >> 32);
      unsigned uu = (uo & 0x80000000u) ? (uo & 0x7FFFFFFFu) : ~uo;
      float sC = __uint_as_float(uu);              // winner: dot - 0.5||e||^2
      int kC = 8191 - (int)(unsigned)(best & 0xFFFFFFFFull);
      float dotw = sC + enh_s[kC - c * 256];       // winner's raw dot (R9 fix)
      if (s2_s[ri] > dotw - MARGIN) {              // another chunk may win
        int pos = atomicAdd(cnt, 1);
        list[pos] = row;
        idx_ws[row] = -(pos + 1);                  // sentinel: resolved via mp2
      } else {
        idx_ws[row] = kC;
      }
    }
  }
}

// Exact fp32 rescore, THREAD-PER-CODE: task j = (flag i, k-chunk kc); each of the
// 256 threads scores one code; block-reduce; one atomicMax(mp2[i]) per block.
__global__ __launch_bounds__(256) void k_cleanup(const float* __restrict__ z,
                                                 const float* __restrict__ en,
                                                 const float* __restrict__ en_h,
                                                 const int* __restrict__ list,
                                                 const int* __restrict__ cnt,
                                                 unsigned long long* __restrict__ mp2) {
  __shared__ unsigned long long wred[4];
  const int tid = threadIdx.x;
  const int lane = tid & 63, wid = tid >> 6;
  const int ntask = (*cnt) * 32;               // 32 chunks of 256 codes per row

  for (int j = blockIdx.x; j < ntask; j += gridDim.x) {
    int i = j >> 5, kc = j & 31;
    int row = list[i];
    const float* zr = z + (size_t)row * D;     // wave-uniform -> scalar loads
    float v[D];
    float ss = 0.f;
#pragma unroll
    for (int d = 0; d < D; ++d) v[d] = zr[d];
#pragma unroll
    for (int d = 0; d < D; ++d) ss = fmaf(v[d], v[d], ss);
    float n = fmaxf(sqrtf(ss), EPS);
#pragma unroll
    for (int d = 0; d < D; ++d) v[d] = v[d] / n;

    int k = kc * 256 + tid;                    // contiguous rows -> coalesced
    const float4* er = reinterpret_cast<const float4*>(en + (size_t)k * D);
    float a = -en_h[k];
#pragma unroll
    for (int jj = 0; jj < 8; ++jj) {           // exact R4 fma order
      float4 e = er[jj];
      a = fmaf(v[4 * jj + 0], e.x, a);
      a = fmaf(v[4 * jj + 1], e.y, a);
      a = fmaf(v[4 * jj + 2], e.z, a);
      a = fmaf(v[4 * jj + 3], e.w, a);
    }
    unsigned o = __float_as_uint(a);
    o = (o & 0x80000000u) ? ~o : (o | 0x80000000u);
    unsigned long long pk = ((unsigned long long)o << 32) | (unsigned)(8191 - k);
#pragma unroll
    for (int m = 32; m >= 1; m >>= 1) {
      unsigned long long op = __shfl_xor(pk, m, 64);
      pk = (op > pk) ? op : pk;                // max s, tie -> min k
    }
    if (lane == 0) wred[wid] = pk;
    __syncthreads();
    if (tid == 0) {
      unsigned long long m01 = (wred[0] > wred[1]) ? wred[0] : wred[1];
      unsigned long long m23 = (wred[2] > wred[3]) ? wred[2] : wred[3];
      atomicMax(&mp2[i], (m01 > m23) ? m01 : m23);
    }
    __syncthreads();                           // protect wred for next task
  }
}

__global__ __launch_bounds__(256) void k_epi(const float* __restrict__ z,
                                             const float* __restrict__ en,
                                             const int* __restrict__ idx_ws,
                                             const unsigned long long* __restrict__ mp2,
                                             float* __restrict__ out_z,
                                             float* __restrict__ loss,
                                             float* __restrict__ out_idx,
                                             float scale) {
  int row = blockIdx.x * 256 + threadIdx.x;
  int kb = idx_ws[row];
  if (kb < 0) {                                // flagged: exact result in mp2
    unsigned long long m = mp2[-kb - 1];
    kb = 8191 - (int)(unsigned)(m & 0xFFFFFFFFull);
  }
  out_idx[row] = (float)kb;  // whole out buffer read back as f32

  const float4* p = reinterpret_cast<const float4*>(z + (size_t)row * D);
  float4 q[D / 4];
#pragma unroll
  for (int j = 0; j < D / 4; ++j) q[j] = p[j];
  float ss = 0.f;
#pragma unroll
  for (int j = 0; j < D / 4; ++j)
    ss = fmaf(q[j].x, q[j].x, fmaf(q[j].y, q[j].y, fmaf(q[j].z, q[j].z, fmaf(q[j].w, q[j].w, ss))));
  float n = fmaxf(sqrtf(ss), EPS);

  const float4* ep = reinterpret_cast<const float4*>(en + (size_t)kb * D);
  float4* op = reinterpret_cast<float4*>(out_z + (size_t)row * D);
  float s = 0.f;
#pragma unroll
  for (int j = 0; j < D / 4; ++j) {
    float4 e = ep[j];
    float4 o;
    o.x = q[j].x + (e.x - q[j].x);  // STE forward value, reference op order
    o.y = q[j].y + (e.y - q[j].y);
    o.z = q[j].z + (e.z - q[j].z);
    o.w = q[j].w + (e.w - q[j].w);
    op[j] = o;
    float dx = e.x - q[j].x / n;  float dy = e.y - q[j].y / n;
    float dz = e.z - q[j].z / n;  float dw = e.w - q[j].w / n;
    s = fmaf(dx, dx, fmaf(dy, dy, fmaf(dz, dz, fmaf(dw, dw, s))));
  }

#pragma unroll
  for (int off = 32; off > 0; off >>= 1) s += __shfl_down(s, off, 64);
  __shared__ float wsum[4];
  int lane = threadIdx.x & 63, wid = threadIdx.x >> 6;
  if (lane == 0) wsum[wid] = s;
  __syncthreads();
  if (threadIdx.x == 0) {
    float tt = (wsum[0] + wsum[1]) + (wsum[2] + wsum[3]);
    atomicAdd(loss, tt * scale);
  }
}

extern "C" void kernel_launch(void* const* d_in, const int* in_sizes, int n_in,
                              void* d_out, int out_size, void* d_ws, size_t ws_size,
                              hipStream_t stream) {
  const float* z = (const float*)d_in[0];
  const float* emb = (const float*)d_in[1];
  const int N = in_sizes[0] / D;  // 32768
  const int K = in_sizes[1] / D;  // 8192

  float* out = (float*)d_out;
  float* out_z = out;                        // N*D
  float* loss = out + (size_t)N * D;         // 1
  float* out_idx = out + (size_t)N * D + 1;  // N

  // ws layout (~8.2 MB)
  char* w = (char*)d_ws;
  float* en = (float*)w;                         w += (size_t)K * D * 4;     // 1 MB
  float* en_h = (float*)w;                       w += (size_t)K * 4;         // 32 KB
  unsigned short* eswz = (unsigned short*)w;     w += (size_t)K * D * 2 * 2; // 1 MB
  unsigned short* zswz_hi = (unsigned short*)w;  w += (size_t)N * D * 2;     // 2 MB
  unsigned short* zswz_lo = (unsigned short*)w;  w += (size_t)N * D * 2;     // 2 MB
  int* idx_ws = (int*)w;                         w += (size_t)N * 4;         // 128 KB
  int* list = (int*)w;                           w += (size_t)N * 4;         // 128 KB
  unsigned long long* mp2 = (unsigned long long*)w; w += (size_t)N * 8;      // 256 KB
  float* res_s1 = (float*)w;                     w += (size_t)N * 4 * 4;     // 512 KB
  int* res_cb = (int*)w;                         w += (size_t)N * 4 * 4;     // 512 KB
  float* res_s2 = (float*)w;                     w += (size_t)N * 4 * 4;     // 512 KB
  int* cnt = (int*)w;

  k_prep<<<dim3((K + N) / 256), 256, 0, stream>>>(
      z, emb, en, en_h, eswz, zswz_hi, zswz_lo, cnt, loss, mp2, N);

  k_argmin_mfma<<<dim3((N / 256) * 4), 256, 0, stream>>>(
      zswz_hi, zswz_lo, eswz, res_s1, res_cb, res_s2);

  k_rescore<<<dim3(32 * 16), 256, 0, stream>>>(
      z, en, en_h, res_s1, res_cb, res_s2, idx_ws, list, cnt, N);

  k_cleanup<<<dim3(4096), 256, 0, stream>>>(z, en, en_h, list, cnt, mp2);

  k_epi<<<dim3(N / 256), 256, 0, stream>>>(
      z, en, idx_ws, mp2, out_z, loss, out_idx, 1.25f / (float)((size_t)N * D));
}

// Round 4
// 172.785 us; speedup vs baseline: 25.9974x; 1.1554x over previous
//
#include <hip/hip_runtime.h>
#include <math.h>

// ViT Vector Quantizer: z [32,1024,32] f32, embedding [8192,32] f32.
// Outputs (concat, read as f32): z_q_out [N*D], loss [1], idx [N] (as floats).
//
// R10: kill k_rescore's VALU waste (58.4 us, 50% VALUBusy, occ 14.6%).
//   - k_prep now also stores normalized z (zn) into the out_z region of d_out
//     (free scratch; k_epi overwrites it last). Same serial fma/sqrt/div order
//     as the old in-kernel normalize -> bitwise identical v[] downstream.
//   - new k_merge: per-row merge of the 4 quarter-results (float4/int4
//     coalesced) -> row_cb, row_s2. Rescore scan reads 4 B/row not 48 B/row.
//   - k_rescore: reads zn (scalar loads), ushort row list, no s2 LDS array
//     (row_s2 read at flag time). LDS 54.8 -> ~41 KB (3 blocks/CU).
//   - k_cleanup: reads zn, drops per-task renormalize.
//   K0 k_prep -> K1 k_argmin_mfma -> K1b k_merge -> K2 k_rescore
//   -> K3 k_cleanup -> K4 k_epi.

#define D 32
#define KCODES 8192
#define MARGIN 2.5e-4f     // ~20x worst-case split-bf16 error bound
#define EPS 1e-12f

typedef short bf16x8 __attribute__((ext_vector_type(8)));
typedef unsigned short u16x8 __attribute__((ext_vector_type(8)));
typedef float f32x4 __attribute__((ext_vector_type(4)));

static __device__ __forceinline__ unsigned short f2bf(float x) {  // RNE bf16 bits
  unsigned u = __float_as_uint(x);
  return (unsigned short)((u + 0x7FFFu + ((u >> 16) & 1u)) >> 16);
}
static __device__ __forceinline__ float bf2f(unsigned short s) {
  return __uint_as_float(((unsigned)s) << 16);
}
static __device__ __forceinline__ void gload_lds16(const void* g, void* l) {
  __builtin_amdgcn_global_load_lds(
      (const __attribute__((address_space(1))) void*)g,
      (__attribute__((address_space(3))) void*)l, 16, 0, 0);
}

// MFMA fragment layouts (validated in prior rounds; A and B mappings are
// identical index formulas, so the same swizzled data serves either operand):
//   A[m][k]: m = lane&15, k = (lane>>4)*8 + j   (8 bf16/lane, contiguous 16B)
//   B[k][n]: n = lane&15, k = (lane>>4)*8 + j
//   C[m][n]: n = lane&15, m = (lane>>4)*4 + reg

__global__ __launch_bounds__(256) void k_prep(const float* __restrict__ z,
                                              const float* __restrict__ emb,
                                              float* __restrict__ en,
                                              float* __restrict__ en_h,
                                              unsigned short* __restrict__ eswz,
                                              unsigned short* __restrict__ zswz_hi,
                                              unsigned short* __restrict__ zswz_lo,
                                              float* __restrict__ zn,
                                              int* __restrict__ cnt,
                                              float* __restrict__ loss,
                                              unsigned long long* __restrict__ mp2,
                                              int N) {
  int v = blockIdx.x * 256 + threadIdx.x;
  if (v == 0) { *cnt = 0; *loss = 0.f; }
  if (v >= KCODES + N) return;
  if (v >= KCODES) mp2[v - KCODES] = 0ull;   // atomicMax identity
  const float* src = (v < KCODES) ? (emb + (size_t)v * D) : (z + (size_t)(v - KCODES) * D);

  float x[D];
  const float4* p = reinterpret_cast<const float4*>(src);
#pragma unroll
  for (int j = 0; j < D / 4; ++j) {
    float4 q = p[j];
    x[4 * j + 0] = q.x; x[4 * j + 1] = q.y; x[4 * j + 2] = q.z; x[4 * j + 3] = q.w;
  }
  float ss = 0.f;
#pragma unroll
  for (int j = 0; j < D; ++j) ss = fmaf(x[j], x[j], ss);
  float n = fmaxf(sqrtf(ss), EPS);
#pragma unroll
  for (int j = 0; j < D; ++j) x[j] = x[j] / n;   // true division mirrors reference

  unsigned short hi[D], lo[D];
#pragma unroll
  for (int j = 0; j < D; ++j) {
    hi[j] = f2bf(x[j]);
    lo[j] = f2bf(x[j] - bf2f(hi[j]));   // x - bf16(x) exact in fp32
  }

  if (v < KCODES) {
    float4* o = reinterpret_cast<float4*>(en + (size_t)v * D);
    float s2 = 0.f;
#pragma unroll
    for (int j = 0; j < D / 4; ++j) {
      float4 q = {x[4 * j], x[4 * j + 1], x[4 * j + 2], x[4 * j + 3]};
      s2 = fmaf(q.x, q.x, fmaf(q.y, q.y, fmaf(q.z, q.z, fmaf(q.w, q.w, s2))));
      o[j] = q;
    }
    en_h[v] = 0.5f * s2;
    int tl = v >> 4, m = v & 15;    // fragment swizzle (tile-of-16 codes)
#pragma unroll
    for (int q = 0; q < 4; ++q) {
      u16x8 hv, lv;
#pragma unroll
      for (int j = 0; j < 8; ++j) { hv[j] = hi[8 * q + j]; lv[j] = lo[8 * q + j]; }
      *(u16x8*)(eswz + (size_t)tl * 1024 + (q * 16 + m) * 8) = hv;
      *(u16x8*)(eswz + (size_t)tl * 1024 + 512 + (q * 16 + m) * 8) = lv;
    }
  } else {
    int r = v - KCODES;
    float4* zo = reinterpret_cast<float4*>(zn + (size_t)r * D);
#pragma unroll
    for (int j = 0; j < D / 4; ++j) {   // bitwise-exact normalized z for
      float4 q = {x[4 * j], x[4 * j + 1], x[4 * j + 2], x[4 * j + 3]};
      zo[j] = q;                        // k_rescore / k_cleanup
    }
    int g = r >> 4, m = r & 15;     // fragment swizzle (group-of-16 rows)
#pragma unroll
    for (int q = 0; q < 4; ++q) {
      u16x8 hv, lv;
#pragma unroll
      for (int j = 0; j < 8; ++j) { hv[j] = hi[8 * q + j]; lv[j] = lo[8 * q + j]; }
      *(u16x8*)(zswz_hi + (size_t)g * 512 + (q * 16 + m) * 8) = hv;
      *(u16x8*)(zswz_lo + (size_t)g * 512 + (q * 16 + m) * 8) = lv;
    }
  }
}

// Deferred-argmax MFMA pass. Grid = (N/256) row-sets x 4 code-quarters.
// Block = 4 waves; each wave holds z-fragments for 4 row-groups (64 rows) so
// one A-fragment (codes) LDS read feeds 12 MFMAs. Per lane: 4 rows (one per
// row-group), 4 scores each per tile, reduced by a fmax tree into a per-chunk
// max. Only (s1, best chunk, other-partial-2nd-best) survive per row-quarter.
__global__ __launch_bounds__(256, 2) void k_argmin_mfma(
    const unsigned short* __restrict__ zswz_hi,
    const unsigned short* __restrict__ zswz_lo,
    const unsigned short* __restrict__ eswz,
    float* __restrict__ res_s1, int* __restrict__ res_cb,
    float* __restrict__ res_s2) {
  __shared__ unsigned short lds_sh[2][16384];   // 2 x 32 KB double buffer

  const int tid = threadIdx.x;
  const int wid = tid >> 6, lane = tid & 63;
  const int lane15 = lane & 15, quad = lane >> 4;
  const int rs = blockIdx.x >> 2;               // row-set (256 rows)
  const int qt = blockIdx.x & 3;                // code quarter (8 chunks)

  bf16x8 zhi[4], zlo[4];
#pragma unroll
  for (int rg = 0; rg < 4; ++rg) {
    int g = rs * 16 + wid * 4 + rg;
    zhi[rg] = *(const bf16x8*)(zswz_hi + (size_t)g * 512 + lane * 8);
    zlo[rg] = *(const bf16x8*)(zswz_lo + (size_t)g * 512 + lane * 8);
  }

  float cm[4], s1g[4], s2c[4];
  int cb[4];
#pragma unroll
  for (int rg = 0; rg < 4; ++rg) {
    cm[rg] = -3.4e38f; s1g[rg] = -3.4e38f; s2c[rg] = -3.4e38f; cb[rg] = 0;
  }
  const f32x4 zero4 = {0.f, 0.f, 0.f, 0.f};

  const float4* gall = reinterpret_cast<const float4*>(eswz) + (size_t)qt * 8 * 2048;
#pragma unroll
  for (int i = 0; i < 8; ++i) {   // stage chunk 0 into buf 0
    int off = i * 256 + tid;      // wave-uniform base + lane-contiguous (m104)
    gload_lds16(gall + off, (char*)&lds_sh[0][0] + (size_t)off * 16);
  }

  for (int c = 0; c < 8; ++c) {
    __syncthreads();              // drains vmcnt -> buffer c&1 fully staged
    if (c + 1 < 8) {              // next DMA overlaps this chunk's compute
      const float4* gn = gall + (size_t)(c + 1) * 2048;
      char* dst = (char*)&lds_sh[(c + 1) & 1][0];
#pragma unroll
      for (int i = 0; i < 8; ++i) {
        int off = i * 256 + tid;
        gload_lds16(gn + off, dst + (size_t)off * 16);
      }
    }
    const unsigned short* buf = &lds_sh[c & 1][0];
#pragma unroll
    for (int t = 0; t < 16; ++t) {
      bf16x8 ahi = *(const bf16x8*)(buf + t * 1024 + lane * 8);
      bf16x8 alo = *(const bf16x8*)(buf + t * 1024 + 512 + lane * 8);
#pragma unroll
      for (int rg = 0; rg < 4; ++rg) {
        // A = codes, B = z: C[m][n] -> n=lane15 = row-in-group, m = code
        f32x4 acc = __builtin_amdgcn_mfma_f32_16x16x32_bf16(ahi, zhi[rg], zero4, 0, 0, 0);
        acc = __builtin_amdgcn_mfma_f32_16x16x32_bf16(ahi, zlo[rg], acc, 0, 0, 0);
        acc = __builtin_amdgcn_mfma_f32_16x16x32_bf16(alo, zhi[rg], acc, 0, 0, 0);
        cm[rg] = fmaxf(cm[rg],
                       fmaxf(fmaxf(acc[0], acc[1]), fmaxf(acc[2], acc[3])));
      }
    }
    // chunk end: fold chunk max into (s1, best chunk, 2nd-best-partial-max)
#pragma unroll
    for (int rg = 0; rg < 4; ++rg) {
      float old1 = s1g[rg];
      s2c[rg] = fmaxf(s2c[rg], fminf(cm[rg], old1));
      bool better = cm[rg] > old1;                // strict: earlier chunk on tie
      cb[rg] = better ? (qt * 8 + c) : cb[rg];
      s1g[rg] = better ? cm[rg] : old1;
      cm[rg] = -3.4e38f;
    }
  }

  // merge the 4 quads (disjoint code subsets of same rows): xor 16 then 32
#pragma unroll
  for (int m = 16; m <= 32; m <<= 1) {
#pragma unroll
    for (int rg = 0; rg < 4; ++rg) {
      float o1 = __shfl_xor(s1g[rg], m, 64);
      float o2 = __shfl_xor(s2c[rg], m, 64);
      int ob = __shfl_xor(cb[rg], m, 64);
      s2c[rg] = fmaxf(fmaxf(s2c[rg], o2), fminf(s1g[rg], o1));
      bool better = o1 > s1g[rg];
      s1g[rg] = better ? o1 : s1g[rg];
      cb[rg] = better ? ob : cb[rg];
    }
  }
  if (quad == 0) {
#pragma unroll
    for (int rg = 0; rg < 4; ++rg) {
      int row = rs * 256 + wid * 64 + rg * 16 + lane15;
      res_s1[(size_t)row * 4 + qt] = s1g[rg];
      res_cb[(size_t)row * 4 + qt] = cb[rg];
      res_s2[(size_t)row * 4 + qt] = s2c[rg];
    }
  }
}

// Per-row merge of the 4 code-quarter results (identical merge math/order to
// R9's in-rescore merge -> bitwise same s1/cb/s2). float4/int4 coalesced.
__global__ __launch_bounds__(256) void k_merge(const float* __restrict__ res_s1,
                                               const int* __restrict__ res_cb,
                                               const float* __restrict__ res_s2,
                                               int* __restrict__ row_cb,
                                               float* __restrict__ row_s2) {
  int row = blockIdx.x * 256 + threadIdx.x;
  float4 s1q = reinterpret_cast<const float4*>(res_s1)[row];
  float4 s2q = reinterpret_cast<const float4*>(res_s2)[row];
  int4 cbq = reinterpret_cast<const int4*>(res_cb)[row];
  float s1b = s1q.x;  int cbb = cbq.x;  float s2b = s2q.x;
  {
    float s1p = s1q.y, s2p = s2q.y; int cbp = cbq.y;
    s2b = fmaxf(fmaxf(s2b, s2p), fminf(s1b, s1p));
    bool better = s1p > s1b;  s1b = better ? s1p : s1b;  cbb = better ? cbp : cbb;
  }
  {
    float s1p = s1q.z, s2p = s2q.z; int cbp = cbq.z;
    s2b = fmaxf(fmaxf(s2b, s2p), fminf(s1b, s1p));
    bool better = s1p > s1b;  s1b = better ? s1p : s1b;  cbb = better ? cbp : cbb;
  }
  {
    float s1p = s1q.w, s2p = s2q.w; int cbp = cbq.w;
    s2b = fmaxf(fmaxf(s2b, s2p), fminf(s1b, s1p));
    bool better = s1p > s1b;  s1b = better ? s1p : s1b;  cbb = better ? cbp : cbb;
  }
  row_cb[row] = cbb;
  row_s2[row] = s2b;
}

// Exact fp32 rescore of each row's winning 256-code chunk.
// Grid = 32 chunks x 16 row-ranges. Block stages its chunk (fp32, padded
// stride 36), scans its 2048-row range (4 B/row: pre-merged row_cb), collects
// matching rows (ushort), then row-per-wave: zn scalar loads (no renormalize),
// 4 codes/lane, packed u64 wave argmax (max s, tie -> min k). Flag test:
// s2 (raw approx dot, from row_s2) vs dotw = sC + en_h[kC] (raw exact dot).
__global__ __launch_bounds__(256) void k_rescore(
    const float* __restrict__ zn, const float* __restrict__ en,
    const float* __restrict__ en_h,
    const int* __restrict__ row_cb, const float* __restrict__ row_s2,
    int* __restrict__ idx_ws, int* __restrict__ list, int* __restrict__ cnt,
    int N) {
  __shared__ float en_s[256 * 36];     // [code][36] padded, 16B-aligned rows
  __shared__ float enh_s[256];
  __shared__ unsigned short rows_s[2048];
  __shared__ int nmatch;

  const int tid = threadIdx.x;
  const int c = blockIdx.x >> 4;       // chunk 0..31
  const int sb = blockIdx.x & 15;      // row sub-range
  const int rows_per = N >> 4;         // 2048
  const int r0 = sb * rows_per;

  if (tid == 0) nmatch = 0;
  // stage chunk: 2048 float4 of en -> padded LDS
  const float4* e4 = reinterpret_cast<const float4*>(en) + (size_t)c * 2048;
#pragma unroll
  for (int i = 0; i < 8; ++i) {
    int idx = i * 256 + tid;
    float4 v4 = e4[idx];
    int code = idx >> 3, j = idx & 7;
    *reinterpret_cast<float4*>(&en_s[code * 36 + j * 4]) = v4;
  }
  enh_s[tid] = en_h[c * 256 + tid];
  __syncthreads();

  // scan rows: collect rows whose (pre-merged) best chunk == c
  for (int i = 0; i < rows_per / 256; ++i) {
    int rrel = i * 256 + tid;
    if (row_cb[r0 + rrel] == c) {
      int pos = atomicAdd(&nmatch, 1);
      rows_s[pos] = (unsigned short)rrel;
    }
  }
  __syncthreads();
  const int nm = nmatch;
  const int lane = tid & 63, wid = tid >> 6;

  for (int ri = wid; ri < nm; ri += 4) {
    int row = __builtin_amdgcn_readfirstlane(r0 + (int)rows_s[ri]);
    const float* znr = zn + (size_t)row * D;   // wave-uniform -> scalar loads
    float v[D];
#pragma unroll
    for (int d = 0; d < D; ++d) v[d] = znr[d];  // bitwise same as old normalize

    unsigned long long best = 0ull;
#pragma unroll
    for (int cc = 0; cc < 4; ++cc) {
      int kl = lane + cc * 64;
      float a = -enh_s[kl];
      const float* ep = &en_s[kl * 36];
#pragma unroll
      for (int jj = 0; jj < 8; ++jj) {             // exact k_cleanup fma order
        float4 e = *reinterpret_cast<const float4*>(&ep[jj * 4]);
        a = fmaf(v[4 * jj + 0], e.x, a);
        a = fmaf(v[4 * jj + 1], e.y, a);
        a = fmaf(v[4 * jj + 2], e.z, a);
        a = fmaf(v[4 * jj + 3], e.w, a);
      }
      int k = c * 256 + kl;
      unsigned o = __float_as_uint(a);
      o = (o & 0x80000000u) ? ~o : (o | 0x80000000u);
      unsigned long long pk = ((unsigned long long)o << 32) | (unsigned)(8191 - k);
      best = (pk > best) ? pk : best;
    }
#pragma unroll
    for (int m = 32; m >= 1; m >>= 1) {
      unsigned long long op = __shfl_xor(best, m, 64);
      best = (op > best) ? op : best;              // max s, tie -> min k
    }
    if (lane == 0) {
      unsigned uo = (unsigned)(best >> 32);
      unsigned uu = (uo & 0x80000000u) ? (uo & 0x7FFFFFFFu) : ~uo;
      float sC = __uint_as_float(uu);              // winner: dot - 0.5||e||^2
      int kC = 8191 - (int)(unsigned)(best & 0xFFFFFFFFull);
      float dotw = sC + enh_s[kC - c * 256];       // winner's raw dot
      if (row_s2[row] > dotw - MARGIN) {           // another chunk may win
        int pos = atomicAdd(cnt, 1);
        list[pos] = row;
        idx_ws[row] = -(pos + 1);                  // sentinel: resolved via mp2
      } else {
        idx_ws[row] = kC;
      }
    }
  }
}

// Exact fp32 rescore, THREAD-PER-CODE: task j = (flag i, k-chunk kc); each of the
// 256 threads scores one code; block-reduce; one atomicMax(mp2[i]) per block.
__global__ __launch_bounds__(256) void k_cleanup(const float* __restrict__ zn,
                                                 const float* __restrict__ en,
                                                 const float* __restrict__ en_h,
                                                 const int* __restrict__ list,
                                                 const int* __restrict__ cnt,
                                                 unsigned long long* __restrict__ mp2) {
  __shared__ unsigned long long wred[4];
  const int tid = threadIdx.x;
  const int lane = tid & 63, wid = tid >> 6;
  const int ntask = (*cnt) * 32;               // 32 chunks of 256 codes per row

  for (int j = blockIdx.x; j < ntask; j += gridDim.x) {
    int i = j >> 5, kc = j & 31;
    int row = list[i];
    const float* znr = zn + (size_t)row * D;   // wave-uniform -> scalar loads
    float v[D];
#pragma unroll
    for (int d = 0; d < D; ++d) v[d] = znr[d]; // bitwise same as old normalize

    int k = kc * 256 + tid;                    // contiguous rows -> coalesced
    const float4* er = reinterpret_cast<const float4*>(en + (size_t)k * D);
    float a = -en_h[k];
#pragma unroll
    for (int jj = 0; jj < 8; ++jj) {           // exact R4 fma order
      float4 e = er[jj];
      a = fmaf(v[4 * jj + 0], e.x, a);
      a = fmaf(v[4 * jj + 1], e.y, a);
      a = fmaf(v[4 * jj + 2], e.z, a);
      a = fmaf(v[4 * jj + 3], e.w, a);
    }
    unsigned o = __float_as_uint(a);
    o = (o & 0x80000000u) ? ~o : (o | 0x80000000u);
    unsigned long long pk = ((unsigned long long)o << 32) | (unsigned)(8191 - k);
#pragma unroll
    for (int m = 32; m >= 1; m >>= 1) {
      unsigned long long op = __shfl_xor(pk, m, 64);
      pk = (op > pk) ? op : pk;                // max s, tie -> min k
    }
    if (lane == 0) wred[wid] = pk;
    __syncthreads();
    if (tid == 0) {
      unsigned long long m01 = (wred[0] > wred[1]) ? wred[0] : wred[1];
      unsigned long long m23 = (wred[2] > wred[3]) ? wred[2] : wred[3];
      atomicMax(&mp2[i], (m01 > m23) ? m01 : m23);
    }
    __syncthreads();                           // protect wred for next task
  }
}

__global__ __launch_bounds__(256) void k_epi(const float* __restrict__ z,
                                             const float* __restrict__ en,
                                             const int* __restrict__ idx_ws,
                                             const unsigned long long* __restrict__ mp2,
                                             float* __restrict__ out_z,
                                             float* __restrict__ loss,
                                             float* __restrict__ out_idx,
                                             float scale) {
  int row = blockIdx.x * 256 + threadIdx.x;
  int kb = idx_ws[row];
  if (kb < 0) {                                // flagged: exact result in mp2
    unsigned long long m = mp2[-kb - 1];
    kb = 8191 - (int)(unsigned)(m & 0xFFFFFFFFull);
  }
  out_idx[row] = (float)kb;  // whole out buffer read back as f32

  const float4* p = reinterpret_cast<const float4*>(z + (size_t)row * D);
  float4 q[D / 4];
#pragma unroll
  for (int j = 0; j < D / 4; ++j) q[j] = p[j];
  float ss = 0.f;
#pragma unroll
  for (int j = 0; j < D / 4; ++j)
    ss = fmaf(q[j].x, q[j].x, fmaf(q[j].y, q[j].y, fmaf(q[j].z, q[j].z, fmaf(q[j].w, q[j].w, ss))));
  float n = fmaxf(sqrtf(ss), EPS);

  const float4* ep = reinterpret_cast<const float4*>(en + (size_t)kb * D);
  float4* op = reinterpret_cast<float4*>(out_z + (size_t)row * D);
  float s = 0.f;
#pragma unroll
  for (int j = 0; j < D / 4; ++j) {
    float4 e = ep[j];
    float4 o;
    o.x = q[j].x + (e.x - q[j].x);  // STE forward value, reference op order
    o.y = q[j].y + (e.y - q[j].y);
    o.z = q[j].z + (e.z - q[j].z);
    o.w = q[j].w + (e.w - q[j].w);
    op[j] = o;
    float dx = e.x - q[j].x / n;  float dy = e.y - q[j].y / n;
    float dz = e.z - q[j].z / n;  float dw = e.w - q[j].w / n;
    s = fmaf(dx, dx, fmaf(dy, dy, fmaf(dz, dz, fmaf(dw, dw, s))));
  }

#pragma unroll
  for (int off = 32; off > 0; off >>= 1) s += __shfl_down(s, off, 64);
  __shared__ float wsum[4];
  int lane = threadIdx.x & 63, wid = threadIdx.x >> 6;
  if (lane == 0) wsum[wid] = s;
  __syncthreads();
  if (threadIdx.x == 0) {
    float tt = (wsum[0] + wsum[1]) + (wsum[2] + wsum[3]);
    atomicAdd(loss, tt * scale);
  }
}

extern "C" void kernel_launch(void* const* d_in, const int* in_sizes, int n_in,
                              void* d_out, int out_size, void* d_ws, size_t ws_size,
                              hipStream_t stream) {
  const float* z = (const float*)d_in[0];
  const float* emb = (const float*)d_in[1];
  const int N = in_sizes[0] / D;  // 32768
  const int K = in_sizes[1] / D;  // 8192

  float* out = (float*)d_out;
  float* out_z = out;                        // N*D
  float* loss = out + (size_t)N * D;         // 1
  float* out_idx = out + (size_t)N * D + 1;  // N

  // zn (normalized z, fp32) lives in the out_z region until k_epi overwrites it
  float* zn = out_z;

  // ws layout (~8.5 MB)
  char* w = (char*)d_ws;
  float* en = (float*)w;                         w += (size_t)K * D * 4;     // 1 MB
  float* en_h = (float*)w;                       w += (size_t)K * 4;         // 32 KB
  unsigned short* eswz = (unsigned short*)w;     w += (size_t)K * D * 2 * 2; // 1 MB
  unsigned short* zswz_hi = (unsigned short*)w;  w += (size_t)N * D * 2;     // 2 MB
  unsigned short* zswz_lo = (unsigned short*)w;  w += (size_t)N * D * 2;     // 2 MB
  int* idx_ws = (int*)w;                         w += (size_t)N * 4;         // 128 KB
  int* list = (int*)w;                           w += (size_t)N * 4;         // 128 KB
  unsigned long long* mp2 = (unsigned long long*)w; w += (size_t)N * 8;      // 256 KB
  float* res_s1 = (float*)w;                     w += (size_t)N * 4 * 4;     // 512 KB
  int* res_cb = (int*)w;                         w += (size_t)N * 4 * 4;     // 512 KB
  float* res_s2 = (float*)w;                     w += (size_t)N * 4 * 4;     // 512 KB
  int* row_cb = (int*)w;                         w += (size_t)N * 4;         // 128 KB
  float* row_s2 = (float*)w;                     w += (size_t)N * 4;         // 128 KB
  int* cnt = (int*)w;

  k_prep<<<dim3((K + N) / 256), 256, 0, stream>>>(
      z, emb, en, en_h, eswz, zswz_hi, zswz_lo, zn, cnt, loss, mp2, N);

  k_argmin_mfma<<<dim3((N / 256) * 4), 256, 0, stream>>>(
      zswz_hi, zswz_lo, eswz, res_s1, res_cb, res_s2);

  k_merge<<<dim3(N / 256), 256, 0, stream>>>(
      res_s1, res_cb, res_s2, row_cb, row_s2);

  k_rescore<<<dim3(32 * 16), 256, 0, stream>>>(
      zn, en, en_h, row_cb, row_s2, idx_ws, list, cnt, N);

  k_cleanup<<<dim3(4096), 256, 0, stream>>>(zn, en, en_h, list, cnt, mp2);

  k_epi<<<dim3(N / 256), 256, 0, stream>>>(
      z, en, idx_ws, mp2, out_z, loss, out_idx, 1.25f / (float)((size_t)N * D));
}